// Round 1
// baseline (4940.282 us; speedup 1.0000x reference)
//
#include <hip/hip_runtime.h>

#define NC    192      // channels
#define NC4   48       // NC/4
#define NTOK  110592   // tokens per batch (48^3)
#define TG    12288    // windows per batch (128*96)
#define WGRID 96       // wg
#define TPB   192
#define NTOKB 18       // tokens per block (2 windows * 9)

// QKV weight staging: 16 chunks x 12 columns (3 float4 per row, 576 rows)
#define QKV_NCH 16
#define QKV_CF4 3
// Proj weight staging: 8 chunks x 24 columns (6 float4 per row, 192 rows, pad to 7)
#define PRJ_NCH 8
#define PRJ_CF4 6
#define PRJ_ROWF4 7

__global__ __launch_bounds__(TPB) void lsa_fused(
    const float* __restrict__ x, const float* __restrict__ Wqkv,
    const float* __restrict__ Wproj, const float* __restrict__ bproj,
    float* __restrict__ out)
{
    __shared__ float XsAo[NTOKB * NC];            // 13824 B; X tokens, later attn-out
    __shared__ float Wlds[576 * QKV_CF4 * 4];     // 27648 B; weight chunk staging
    __shared__ float Slds[2 * 6 * 9 * 9];         // 3888 B; scores / probs

    const int tid = threadIdx.x;

    // ---- window geometry (2 windows per block) ----
    const int wid0 = blockIdx.x * 2;
    const int wid1 = wid0 + 1;
    const int b0 = wid0 / TG, g0 = wid0 % TG;
    const int b1 = wid1 / TG, g1 = wid1 % TG;
    // token row for (window, i, j): nbase + i*288 + j   [288 = 3*WGRID]
    const long nb0 = (long)(g0 / WGRID) * 864 + (long)(g0 % WGRID) * 3;
    const long nb1 = (long)(g1 / WGRID) * 864 + (long)(g1 % WGRID) * 3;
    const long base0 = ((long)b0 * NTOK + nb0);
    const long base1 = ((long)b1 * NTOK + nb1);

    // ---- phase 0: load 18 token rows of X into LDS ----
    {
        float4* Xs4 = (float4*)XsAo;
        const float4* x4 = (const float4*)x;
        for (int l = tid; l < NTOKB * NC4; l += TPB) {
            int t = l / NC4, c4 = l % NC4;
            int tl = (t < 9) ? t : t - 9;
            long base = (t < 9) ? base0 : base1;
            int i = tl / 3, j = tl % 3;
            long row = base + i * 288 + j;
            Xs4[l] = x4[row * NC4 + c4];
        }
    }

    // ---- phase 1: QKV projection ----
    // thread owns outputs o = tid (q), 192+tid (k), 384+tid (v)
    // => head h = tid>>5, dim d = tid&31, for all 18 tokens
    float q[NTOKB], k[NTOKB], v[NTOKB];
    #pragma unroll
    for (int t = 0; t < NTOKB; ++t) { q[t] = 0.f; k[t] = 0.f; v[t] = 0.f; }

    {
        const float4* Wq4 = (const float4*)Wqkv;
        float4* Wl4 = (float4*)Wlds;
        const float4* Xs4 = (const float4*)XsAo;
        for (int ch = 0; ch < QKV_NCH; ++ch) {
            __syncthreads();   // previous chunk's readers done
            for (int l = tid; l < 576 * QKV_CF4; l += TPB) {
                int row = l / QKV_CF4, c4l = l % QKV_CF4;
                Wl4[l] = Wq4[row * NC4 + ch * QKV_CF4 + c4l];
            }
            __syncthreads();
            #pragma unroll
            for (int c4l = 0; c4l < QKV_CF4; ++c4l) {
                float4 w0 = Wl4[(0   + tid) * QKV_CF4 + c4l];
                float4 w1 = Wl4[(192 + tid) * QKV_CF4 + c4l];
                float4 w2 = Wl4[(384 + tid) * QKV_CF4 + c4l];
                #pragma unroll
                for (int t = 0; t < NTOKB; ++t) {
                    float4 xv = Xs4[t * NC4 + ch * QKV_CF4 + c4l];
                    q[t] = fmaf(w0.x, xv.x, q[t]);
                    q[t] = fmaf(w0.y, xv.y, q[t]);
                    q[t] = fmaf(w0.z, xv.z, q[t]);
                    q[t] = fmaf(w0.w, xv.w, q[t]);
                    k[t] = fmaf(w1.x, xv.x, k[t]);
                    k[t] = fmaf(w1.y, xv.y, k[t]);
                    k[t] = fmaf(w1.z, xv.z, k[t]);
                    k[t] = fmaf(w1.w, xv.w, k[t]);
                    v[t] = fmaf(w2.x, xv.x, v[t]);
                    v[t] = fmaf(w2.y, xv.y, v[t]);
                    v[t] = fmaf(w2.z, xv.z, v[t]);
                    v[t] = fmaf(w2.w, xv.w, v[t]);
                }
            }
        }
    }

    // ---- phase 2: scores via 32-lane shuffle reduction over d ----
    const int h = tid >> 5;
    const int d = tid & 31;
    {
        #pragma unroll
        for (int wl = 0; wl < 2; ++wl)
        {
            #pragma unroll
            for (int qi = 0; qi < 9; ++qi)
            {
                #pragma unroll
                for (int ki = 0; ki < 9; ++ki) {
                    float p = q[wl * 9 + qi] * k[wl * 9 + ki];
                    p += __shfl_xor(p, 1);
                    p += __shfl_xor(p, 2);
                    p += __shfl_xor(p, 4);
                    p += __shfl_xor(p, 8);
                    p += __shfl_xor(p, 16);
                    if (d == 0) Slds[((wl * 6 + h) * 9 + qi) * 9 + ki] = p;
                }
            }
        }
    }
    __syncthreads();

    // ---- phase 3: softmax (108 rows: 2 windows * 6 heads * 9 query rows) ----
    if (tid < 108) {
        const int wl = tid / 54, rem = tid % 54;
        const int hh = rem / 9, qi = rem % 9;
        float* srow = &Slds[((wl * 6 + hh) * 9 + qi) * 9];
        float mx = srow[0];
        #pragma unroll
        for (int ki = 1; ki < 9; ++ki) mx = fmaxf(mx, srow[ki]);
        float e[9];
        float sum = 0.f;
        #pragma unroll
        for (int ki = 0; ki < 9; ++ki) {
            e[ki] = __expf((srow[ki] - mx) * 0.17677669529663687f); // scale = 1/sqrt(32)
            sum += e[ki];
        }
        float inv = 1.0f / sum;
        #pragma unroll
        for (int ki = 0; ki < 9; ++ki) srow[ki] = e[ki] * inv;
    }
    __syncthreads();

    // ---- phase 4: PV (p from LDS broadcast, v in registers) ----
    float o_[NTOKB];
    #pragma unroll
    for (int wl = 0; wl < 2; ++wl)
    {
        #pragma unroll
        for (int qi = 0; qi < 9; ++qi) {
            const float* prow = &Slds[((wl * 6 + h) * 9 + qi) * 9];
            float acc = 0.f;
            #pragma unroll
            for (int ki = 0; ki < 9; ++ki)
                acc = fmaf(prow[ki], v[wl * 9 + ki], acc);
            o_[wl * 9 + qi] = acc;
        }
    }
    // stash attention output (token t, channel tid) into LDS (aliases Xs; safe:
    // last Xs read was before the two barriers above)
    #pragma unroll
    for (int t = 0; t < NTOKB; ++t) XsAo[t * NC + tid] = o_[t];
    // (barrier before reads happens at top of proj chunk loop)

    // ---- phase 5: output projection ----
    {
        const float4* Wp4 = (const float4*)Wproj;
        float4* Wl4 = (float4*)Wlds;
        const float4* Ao4 = (const float4*)XsAo;
        const int wl = tid / 96;       // window handled by this thread
        const int cp = tid % 96;       // output channels cp and cp+96
        float pa[NTOKB];
        #pragma unroll
        for (int t = 0; t < NTOKB; ++t) pa[t] = 0.f;

        for (int ch = 0; ch < PRJ_NCH; ++ch) {
            __syncthreads();   // ao writes done (ch=0) / previous chunk readers done
            for (int l = tid; l < 192 * PRJ_CF4; l += TPB) {
                int row = l / PRJ_CF4, c4l = l % PRJ_CF4;
                Wl4[row * PRJ_ROWF4 + c4l] = Wp4[row * NC4 + ch * PRJ_CF4 + c4l];
            }
            __syncthreads();
            #pragma unroll
            for (int c4l = 0; c4l < PRJ_CF4; ++c4l) {
                float4 w0 = Wl4[cp * PRJ_ROWF4 + c4l];
                float4 w1 = Wl4[(cp + 96) * PRJ_ROWF4 + c4l];
                #pragma unroll
                for (int qi = 0; qi < 9; ++qi) {
                    float4 av = Ao4[(wl * 9 + qi) * NC4 + ch * PRJ_CF4 + c4l];
                    pa[qi]     = fmaf(w0.x, av.x, pa[qi]);
                    pa[qi]     = fmaf(w0.y, av.y, pa[qi]);
                    pa[qi]     = fmaf(w0.z, av.z, pa[qi]);
                    pa[qi]     = fmaf(w0.w, av.w, pa[qi]);
                    pa[9 + qi] = fmaf(w1.x, av.x, pa[9 + qi]);
                    pa[9 + qi] = fmaf(w1.y, av.y, pa[9 + qi]);
                    pa[9 + qi] = fmaf(w1.z, av.z, pa[9 + qi]);
                    pa[9 + qi] = fmaf(w1.w, av.w, pa[9 + qi]);
                }
            }
        }

        const float bv0 = bproj[cp];
        const float bv1 = bproj[cp + 96];
        const long base = (wl == 0) ? base0 : base1;
        #pragma unroll
        for (int qi = 0; qi < 9; ++qi) {
            int i = qi / 3, j = qi % 3;
            long row = base + i * 288 + j;
            float* dst = out + row * NC;
            dst[cp]      = pa[qi] + bv0;
            dst[cp + 96] = pa[9 + qi] + bv1;
        }
    }
}

extern "C" void kernel_launch(void* const* d_in, const int* in_sizes, int n_in,
                              void* d_out, int out_size, void* d_ws, size_t ws_size,
                              hipStream_t stream) {
    const float* x     = (const float*)d_in[0];
    const float* Wqkv  = (const float*)d_in[1];
    const float* Wproj = (const float*)d_in[2];
    const float* bproj = (const float*)d_in[3];
    float* out = (float*)d_out;
    // 24576 windows total, 2 per block
    lsa_fused<<<12288, TPB, 0, stream>>>(x, Wqkv, Wproj, bproj, out);
}

// Round 2
// 405.400 us; speedup vs baseline: 12.1862x; 12.1862x over previous
//
#include <hip/hip_runtime.h>

typedef _Float16 f16;
typedef _Float16 f16x8 __attribute__((ext_vector_type(8)));
typedef float f32x4 __attribute__((ext_vector_type(4)));

#define TPB 576            // 9 waves
#define NWIN 16            // windows per block
#define XS 200             // Xh row stride (halves)
#define WSS 200            // Wh row stride (halves)
#define QS 40              // Qh/Kh/Pb/AOh/Wph row stride (halves)
#define VS 280             // Vt2 row stride (halves)

__global__ __launch_bounds__(TPB) void lsa_mfma(
    const float* __restrict__ x, const float* __restrict__ Wqkv,
    const float* __restrict__ Wproj, const float* __restrict__ bproj,
    float* __restrict__ out)
{
    // LDS plan (bytes): Xh 57600 | Wh 38400 (aliased by Wph 15360) | Qh 12160 |
    // Kh 12160 | Vt2 17920 | Pb 12160 | AOh 11520  => 161920 B total
    __shared__ f16 Xh[144 * XS];
    __shared__ f16 Wh[96 * WSS];
    __shared__ f16 Qh[152 * QS];
    __shared__ f16 Kh[152 * QS];
    __shared__ f16 Vt2[32 * VS];
    __shared__ f16 Pb[152 * QS];
    __shared__ f16 AOh[144 * QS];

    const int tid  = threadIdx.x;
    const int lane = tid & 63;
    const int w    = tid >> 6;      // wave 0..8
    const int mi   = w / 3;         // M-group 0..2
    const int ni   = w % 3;         // N-group 0..2
    const int l15  = lane & 15;
    const int lg   = lane >> 4;     // 0..3

    // ---- geometry: 16 windows per block, never straddles batch or row-group ----
    const int  bb    = blockIdx.x / 768;
    const int  gbase = (blockIdx.x % 768) * NWIN;
    const long rb0   = (long)bb * 110592 + (long)(gbase / 96) * 864 + (long)(gbase % 96) * 3;
    // token t (0..143): wi=t/9, q=t%9 ; global row = rb0 + wi*3 + (q/3)*288 + q%3

    // ---- phase 0: X -> LDS fp16 ----
    for (int idx = tid; idx < 144 * 48; idx += TPB) {   // 12 exact iters
        int t = idx / 48, c4 = idx % 48;
        int wi = t / 9, q = t - 9 * wi;
        long grow = rb0 + wi * 3 + (q / 3) * 288 + (q % 3);
        float4 xv = ((const float4*)x)[grow * 48 + c4];
        union { f16 h[4]; ushort4 u; } tmp;
        tmp.h[0] = (f16)xv.x; tmp.h[1] = (f16)xv.y; tmp.h[2] = (f16)xv.z; tmp.h[3] = (f16)xv.w;
        *(ushort4*)&Xh[t * XS + c4 * 4] = tmp.u;
    }
    // zero Pb and Vt2 (dead slots must be finite: 0 * garbage-NaN would poison PV)
    {
        int4 z = {0, 0, 0, 0};
        for (int i2 = tid; i2 < (152 * QS * 2) / 16; i2 += TPB) ((int4*)Pb)[i2]  = z;
        for (int i2 = tid; i2 < (32 * VS * 2) / 16;  i2 += TPB) ((int4*)Vt2)[i2] = z;
    }

    // proj accumulators: wave owns mtiles 3mi..3mi+2  x  ntiles 4ni..4ni+3
    f32x4 pacc[3][4];
    #pragma unroll
    for (int a = 0; a < 3; ++a)
        #pragma unroll
        for (int bq = 0; bq < 4; ++bq)
            pacc[a][bq] = (f32x4){0.f, 0.f, 0.f, 0.f};

    __syncthreads();

    for (int h = 0; h < 6; ++h) {
        // ---- stage Wqkv rows for head h: local rows 0..31=Q, 32..63=K, 64..95=V ----
        for (int idx = tid; idx < 96 * 48; idx += TPB) {  // 8 exact iters
            int r = idx / 48, c4 = idx % 48;
            int grp = r >> 5;
            int grow = grp * 192 + h * 32 + (r & 31);
            float4 wv = ((const float4*)Wqkv)[grow * 48 + c4];
            union { f16 h4[4]; ushort4 u; } tmp;
            tmp.h4[0] = (f16)wv.x; tmp.h4[1] = (f16)wv.y; tmp.h4[2] = (f16)wv.z; tmp.h4[3] = (f16)wv.w;
            *(ushort4*)&Wh[r * WSS + c4 * 4] = tmp.u;
        }
        __syncthreads();

        // ---- QKV GEMM: X(144x192) @ Wh(96x192)^T ----
        f32x4 qacc[3][2];
        #pragma unroll
        for (int a = 0; a < 3; ++a)
            #pragma unroll
            for (int c = 0; c < 2; ++c)
                qacc[a][c] = (f32x4){0.f, 0.f, 0.f, 0.f};
        #pragma unroll
        for (int kk = 0; kk < 6; ++kk) {
            f16x8 af[3], bf[2];
            #pragma unroll
            for (int a = 0; a < 3; ++a)
                af[a] = *(const f16x8*)&Xh[(16 * (3 * mi + a) + l15) * XS + kk * 32 + lg * 8];
            #pragma unroll
            for (int c = 0; c < 2; ++c)
                bf[c] = *(const f16x8*)&Wh[(16 * (2 * ni + c) + l15) * WSS + kk * 32 + lg * 8];
            #pragma unroll
            for (int a = 0; a < 3; ++a)
                #pragma unroll
                for (int c = 0; c < 2; ++c)
                    qacc[a][c] = __builtin_amdgcn_mfma_f32_16x16x32_f16(af[a], bf[c], qacc[a][c], 0, 0, 0);
        }
        // scatter D-frags: col = l15 (channel), row = lg*4+r (token)
        #pragma unroll
        for (int a = 0; a < 3; ++a) {
            const int trow = 16 * (3 * mi + a) + lg * 4;
            #pragma unroll
            for (int c = 0; c < 2; ++c) {
                const int nt = 2 * ni + c;      // 0..5, wave-uniform
                if (nt < 2) {                   // Q: d = nt*16 + l15
                    const int d = nt * 16 + l15;
                    #pragma unroll
                    for (int r = 0; r < 4; ++r)
                        Qh[(trow + r) * QS + d] = (f16)qacc[a][c][r];
                } else if (nt < 4) {            // K
                    const int d = (nt - 2) * 16 + l15;
                    #pragma unroll
                    for (int r = 0; r < 4; ++r)
                        Kh[(trow + r) * QS + d] = (f16)qacc[a][c][r];
                } else {                        // V -> window-slot-aligned transpose
                    const int d = (nt - 4) * 16 + l15;
                    #pragma unroll
                    for (int r = 0; r < 4; ++r) {
                        int t = trow + r;
                        int wi = t / 9, qq = t - 9 * wi;
                        Vt2[d * VS + 16 * wi + qq] = (f16)qacc[a][c][r];
                    }
                }
            }
        }
        __syncthreads();

        // ---- stage Wproj slice (cols h*32..h*32+31) into Wh alias; read after PV sync ----
        f16* Wph = Wh;
        for (int idx = tid; idx < 192 * 8; idx += TPB) {
            int r = idx / 8, c4 = idx % 8;
            float4 wv = ((const float4*)Wproj)[r * 48 + h * 8 + c4];
            union { f16 h4[4]; ushort4 u; } tmp;
            tmp.h4[0] = (f16)wv.x; tmp.h4[1] = (f16)wv.y; tmp.h4[2] = (f16)wv.z; tmp.h4[3] = (f16)wv.w;
            *(ushort4*)&Wph[r * QS + c4 * 4] = tmp.u;
        }

        // ---- scores + softmax: one MFMA per window ----
        for (int wi = w; wi < NWIN; wi += 9) {
            f16x8 aq = *(const f16x8*)&Qh[(9 * wi + l15) * QS + lg * 8];
            f16x8 bk = *(const f16x8*)&Kh[(9 * wi + l15) * QS + lg * 8];
            f32x4 s = (f32x4){0.f, 0.f, 0.f, 0.f};
            s = __builtin_amdgcn_mfma_f32_16x16x32_f16(aq, bk, s, 0, 0, 0);
            // D: col=l15=key, row=lg*4+r=q (window-local)
            #pragma unroll
            for (int r = 0; r < 4; ++r) {
                float lgt = (l15 < 9) ? s[r] * 0.17677669529663687f : -1e30f;
                float mx = lgt;
                mx = fmaxf(mx, __shfl_xor(mx, 1));
                mx = fmaxf(mx, __shfl_xor(mx, 2));
                mx = fmaxf(mx, __shfl_xor(mx, 4));
                mx = fmaxf(mx, __shfl_xor(mx, 8));
                float e = __expf(lgt - mx);
                float sm = e;
                sm += __shfl_xor(sm, 1);
                sm += __shfl_xor(sm, 2);
                sm += __shfl_xor(sm, 4);
                sm += __shfl_xor(sm, 8);
                int q = lg * 4 + r;
                if (q < 9) Pb[(9 * wi + q) * QS + l15] = (f16)(e / sm);
            }
        }
        __syncthreads();

        // ---- PV: O(9x32) = P(9x9,padded) @ V ----
        for (int wi = w; wi < NWIN; wi += 9) {
            f16x8 ap = *(const f16x8*)&Pb[(9 * wi + l15) * QS + lg * 8];
            #pragma unroll
            for (int dt = 0; dt < 2; ++dt) {
                f16x8 bv = *(const f16x8*)&Vt2[(dt * 16 + l15) * VS + 16 * wi + lg * 8];
                f32x4 o = (f32x4){0.f, 0.f, 0.f, 0.f};
                o = __builtin_amdgcn_mfma_f32_16x16x32_f16(ap, bv, o, 0, 0, 0);
                #pragma unroll
                for (int r = 0; r < 4; ++r) {
                    int q = lg * 4 + r;
                    if (q < 9) AOh[(9 * wi + q) * QS + dt * 16 + l15] = (f16)o[r];
                }
            }
        }
        __syncthreads();

        // ---- proj partial: out += AO_h(144x32) @ Wproj_h(192x32)^T ----
        {
            f16x8 aof[3];
            #pragma unroll
            for (int a = 0; a < 3; ++a)
                aof[a] = *(const f16x8*)&AOh[(16 * (3 * mi + a) + l15) * QS + lg * 8];
            #pragma unroll
            for (int bq = 0; bq < 4; ++bq) {
                f16x8 bw = *(const f16x8*)&Wph[(16 * (4 * ni + bq) + l15) * QS + lg * 8];
                #pragma unroll
                for (int a = 0; a < 3; ++a)
                    pacc[a][bq] = __builtin_amdgcn_mfma_f32_16x16x32_f16(aof[a], bw, pacc[a][bq], 0, 0, 0);
            }
        }
        __syncthreads();   // protects Wh/Qh/Kh/Vt2/Pb/AOh rewrite next head
    }

    // ---- epilogue: pacc + bias -> out ----
    float bv[4];
    #pragma unroll
    for (int bq = 0; bq < 4; ++bq)
        bv[bq] = bproj[16 * (4 * ni + bq) + l15];
    #pragma unroll
    for (int a = 0; a < 3; ++a) {
        #pragma unroll
        for (int r = 0; r < 4; ++r) {
            int t = 16 * (3 * mi + a) + lg * 4 + r;
            int wi = t / 9, q = t - 9 * wi;
            long grow = rb0 + wi * 3 + (q / 3) * 288 + (q % 3);
            float* dst = out + grow * 192;
            #pragma unroll
            for (int bq = 0; bq < 4; ++bq)
                dst[16 * (4 * ni + bq) + l15] = pacc[a][bq][r] + bv[bq];
        }
    }
}

extern "C" void kernel_launch(void* const* d_in, const int* in_sizes, int n_in,
                              void* d_out, int out_size, void* d_ws, size_t ws_size,
                              hipStream_t stream) {
    const float* x     = (const float*)d_in[0];
    const float* Wqkv  = (const float*)d_in[1];
    const float* Wproj = (const float*)d_in[2];
    const float* bproj = (const float*)d_in[3];
    float* out = (float*)d_out;
    // 24576 windows total, 16 per block
    lsa_mfma<<<1536, TPB, 0, stream>>>(x, Wqkv, Wproj, bproj, out);
}